// Round 1
// baseline (246.957 us; speedup 1.0000x reference)
//
#include <hip/hip_runtime.h>

#define Bx 64
#define Cx 3
#define HIx 224
#define WIx 224
#define Hx 32
#define Wx 64
#define URx 10
#define UTx 10
#define HGx (URx*Hx)   // 320
#define WGx (Wx*UTx)   // 640

// ---------------- transpose CHW -> HWC4 (channel-pad to 4) ----------------
__global__ __launch_bounds__(256)
void transpose_hwc4(const float* __restrict__ x, float4* __restrict__ xt) {
    int tid = blockIdx.x * blockDim.x + threadIdx.x;  // over B*HI*WI
    const int total = Bx * HIx * WIx;
    if (tid >= total) return;
    int b = tid / (HIx * WIx);
    int hw = tid - b * (HIx * WIx);
    const float* xb = x + (size_t)b * Cx * HIx * WIx + hw;
    float4 v;
    v.x = xb[0];
    v.y = xb[HIx * WIx];
    v.z = xb[2 * HIx * WIx];
    v.w = 0.f;
    xt[tid] = v;
}

// ---------------- fast sampler: HWC4 layout, float4 taps ----------------
__global__ __launch_bounds__(256)
void sample_hwc4(const float4* __restrict__ xt,
                 const float* __restrict__ lt,
                 const float2* __restrict__ grid,
                 float* __restrict__ out) {
    int tid = blockIdx.x * blockDim.x + threadIdx.x;  // B*H*W = 131072
    int b  = tid >> 11;         // / (H*W)
    int oh = (tid >> 6) & 31;
    int ow = tid & 63;
    float lx = lt[2 * b];
    float ly = lt[2 * b + 1];
    const float4* xb = xt + (size_t)b * HIx * WIx;
    float a0 = 0.f, a1 = 0.f, a2 = 0.f;
    int grow0 = oh * URx;
    int gcol0 = ow * UTx;
    for (int gi = 0; gi < URx; ++gi) {
        const float2* grow = grid + (size_t)(grow0 + gi) * WGx + gcol0;
#pragma unroll
        for (int gj = 0; gj < UTx; ++gj) {
            float2 g = grow[gj];
            float ix = (g.x + lx) * (WIx * 0.5f) + (WIx - 1) * 0.5f;
            float iy = (g.y + ly) * (HIx * 0.5f) + (HIx - 1) * 0.5f;
            float x0f = floorf(ix), y0f = floorf(iy);
            float fx = ix - x0f, fy = iy - y0f;
            int x0 = (int)x0f, y0 = (int)y0f;
            int x1 = x0 + 1, y1 = y0 + 1;
            float wx0 = 1.f - fx, wy0 = 1.f - fy;
            bool vx0 = ((unsigned)x0 < (unsigned)WIx);
            bool vx1 = ((unsigned)x1 < (unsigned)WIx);
            bool vy0 = ((unsigned)y0 < (unsigned)HIx);
            bool vy1 = ((unsigned)y1 < (unsigned)HIx);
            int xc0 = min(max(x0, 0), WIx - 1), xc1 = min(max(x1, 0), WIx - 1);
            int yc0 = min(max(y0, 0), HIx - 1), yc1 = min(max(y1, 0), HIx - 1);
            float w00 = wx0 * wy0 * ((vx0 && vy0) ? 1.f : 0.f);
            float w01 = fx  * wy0 * ((vx1 && vy0) ? 1.f : 0.f);
            float w10 = wx0 * fy  * ((vx0 && vy1) ? 1.f : 0.f);
            float w11 = fx  * fy  * ((vx1 && vy1) ? 1.f : 0.f);
            float4 v00 = xb[yc0 * WIx + xc0];
            float4 v01 = xb[yc0 * WIx + xc1];
            float4 v10 = xb[yc1 * WIx + xc0];
            float4 v11 = xb[yc1 * WIx + xc1];
            a0 += w00 * v00.x + w01 * v01.x + w10 * v10.x + w11 * v11.x;
            a1 += w00 * v00.y + w01 * v01.y + w10 * v10.y + w11 * v11.y;
            a2 += w00 * v00.z + w01 * v01.z + w10 * v10.z + w11 * v11.z;
        }
    }
    const float s = 1.0f / (URx * UTx);
    int obase = b * (Cx * Hx * Wx) + oh * Wx + ow;
    out[obase]             = a0 * s;
    out[obase + Hx * Wx]     = a1 * s;
    out[obase + 2 * Hx * Wx] = a2 * s;
}

// ---------------- fallback sampler: direct CHW gathers ----------------
__global__ __launch_bounds__(256)
void sample_chw(const float* __restrict__ x,
                const float* __restrict__ lt,
                const float2* __restrict__ grid,
                float* __restrict__ out) {
    int tid = blockIdx.x * blockDim.x + threadIdx.x;
    int b  = tid >> 11;
    int oh = (tid >> 6) & 31;
    int ow = tid & 63;
    float lx = lt[2 * b];
    float ly = lt[2 * b + 1];
    const float* xb = x + (size_t)b * Cx * HIx * WIx;
    float a0 = 0.f, a1 = 0.f, a2 = 0.f;
    int grow0 = oh * URx;
    int gcol0 = ow * UTx;
    for (int gi = 0; gi < URx; ++gi) {
        const float2* grow = grid + (size_t)(grow0 + gi) * WGx + gcol0;
#pragma unroll
        for (int gj = 0; gj < UTx; ++gj) {
            float2 g = grow[gj];
            float ix = (g.x + lx) * (WIx * 0.5f) + (WIx - 1) * 0.5f;
            float iy = (g.y + ly) * (HIx * 0.5f) + (HIx - 1) * 0.5f;
            float x0f = floorf(ix), y0f = floorf(iy);
            float fx = ix - x0f, fy = iy - y0f;
            int x0 = (int)x0f, y0 = (int)y0f;
            int x1 = x0 + 1, y1 = y0 + 1;
            float wx0 = 1.f - fx, wy0 = 1.f - fy;
            bool vx0 = ((unsigned)x0 < (unsigned)WIx);
            bool vx1 = ((unsigned)x1 < (unsigned)WIx);
            bool vy0 = ((unsigned)y0 < (unsigned)HIx);
            bool vy1 = ((unsigned)y1 < (unsigned)HIx);
            int xc0 = min(max(x0, 0), WIx - 1), xc1 = min(max(x1, 0), WIx - 1);
            int yc0 = min(max(y0, 0), HIx - 1), yc1 = min(max(y1, 0), HIx - 1);
            float w00 = wx0 * wy0 * ((vx0 && vy0) ? 1.f : 0.f);
            float w01 = fx  * wy0 * ((vx1 && vy0) ? 1.f : 0.f);
            float w10 = wx0 * fy  * ((vx0 && vy1) ? 1.f : 0.f);
            float w11 = fx  * fy  * ((vx1 && vy1) ? 1.f : 0.f);
            int i00 = yc0 * WIx + xc0;
            int i01 = yc0 * WIx + xc1;
            int i10 = yc1 * WIx + xc0;
            int i11 = yc1 * WIx + xc1;
            a0 += w00 * xb[i00] + w01 * xb[i01] + w10 * xb[i10] + w11 * xb[i11];
            const float* xb1 = xb + HIx * WIx;
            a1 += w00 * xb1[i00] + w01 * xb1[i01] + w10 * xb1[i10] + w11 * xb1[i11];
            const float* xb2 = xb + 2 * HIx * WIx;
            a2 += w00 * xb2[i00] + w01 * xb2[i01] + w10 * xb2[i10] + w11 * xb2[i11];
        }
    }
    const float s = 1.0f / (URx * UTx);
    int obase = b * (Cx * Hx * Wx) + oh * Wx + ow;
    out[obase]             = a0 * s;
    out[obase + Hx * Wx]     = a1 * s;
    out[obase + 2 * Hx * Wx] = a2 * s;
}

extern "C" void kernel_launch(void* const* d_in, const int* in_sizes, int n_in,
                              void* d_out, int out_size, void* d_ws, size_t ws_size,
                              hipStream_t stream) {
    const float*  x    = (const float*)d_in[0];
    const float*  lt   = (const float*)d_in[1];
    const float2* grid = (const float2*)d_in[2];
    float* out = (float*)d_out;

    const size_t need = (size_t)Bx * HIx * WIx * 4 * sizeof(float);  // 51.4 MB
    const int n_out_threads = Bx * Hx * Wx;  // 131072

    if (ws_size >= need) {
        float4* xt = (float4*)d_ws;
        const int total = Bx * HIx * WIx;
        transpose_hwc4<<<(total + 255) / 256, 256, 0, stream>>>(x, xt);
        sample_hwc4<<<n_out_threads / 256, 256, 0, stream>>>(xt, lt, grid, out);
    } else {
        sample_chw<<<n_out_threads / 256, 256, 0, stream>>>(x, lt, grid, out);
    }
}

// Round 2
// 223.020 us; speedup vs baseline: 1.1073x; 1.1073x over previous
//
#include <hip/hip_runtime.h>

#define Bx 64
#define Cx 3
#define HIx 224
#define WIx 224
#define Hx 32
#define Wx 64
#define URx 10
#define UTx 10
#define HGx (URx*Hx)   // 320
#define WGx (Wx*UTx)   // 640

// ---------------- transpose CHW -> HWC4, 4 pixels per thread ----------------
__global__ __launch_bounds__(256)
void transpose_hwc4(const float4* __restrict__ x, float4* __restrict__ xt) {
    int tid = blockIdx.x * blockDim.x + threadIdx.x;  // over B*HI*WI/4
    const int total4 = Bx * HIx * WIx / 4;
    if (tid >= total4) return;
    const int hw4 = HIx * WIx / 4;  // 12544
    int b = tid / hw4;
    int p = tid - b * hw4;
    const float4* xb = x + (size_t)b * Cx * hw4 + p;
    float4 c0 = xb[0];
    float4 c1 = xb[hw4];
    float4 c2 = xb[2 * hw4];
    float4* o = xt + 4 * (size_t)tid;
    o[0] = make_float4(c0.x, c1.x, c2.x, 0.f);
    o[1] = make_float4(c0.y, c1.y, c2.y, 0.f);
    o[2] = make_float4(c0.z, c1.z, c2.z, 0.f);
    o[3] = make_float4(c0.w, c1.w, c2.w, 0.f);
}

// ---------------- sampler: 4 lanes per output pixel, 25 samples each --------
__global__ __launch_bounds__(256)
void sample_hwc4(const float4* __restrict__ xt,
                 const float* __restrict__ lt,
                 const float2* __restrict__ grid,
                 float* __restrict__ out) {
    int tid = blockIdx.x * blockDim.x + threadIdx.x;  // 4 * B*H*W threads
    int lane4 = tid & 3;
    int pix = tid >> 2;
    int b  = pix >> 11;          // / (H*W)
    int oh = (pix >> 6) & 31;
    int ow = pix & 63;

    float lx = lt[2 * b];
    float ly = lt[2 * b + 1];
    // ix = (gx+lx)*Wi/2 + (Wi-1)/2  ->  fma(gx, 112, cx)
    float cxc = lx * (WIx * 0.5f) + (WIx - 1) * 0.5f;
    float cyc = ly * (HIx * 0.5f) + (HIx - 1) * 0.5f;

    const float4* xb = xt + (size_t)b * HIx * WIx;
    int gbase = (oh * URx) * WGx + ow * UTx;

    float a0 = 0.f, a1 = 0.f, a2 = 0.f;
    int s0 = lane4 * 25;
#pragma unroll 5
    for (int t = 0; t < 25; ++t) {
        int s = s0 + t;
        int gi = s / 10;
        int gj = s - 10 * gi;
        float2 g = grid[gbase + gi * WGx + gj];
        float ix = fmaf(g.x, (WIx * 0.5f), cxc);
        float iy = fmaf(g.y, (HIx * 0.5f), cyc);
        float x0f = floorf(ix), y0f = floorf(iy);
        float fx = ix - x0f, fy = iy - y0f;
        int x0 = (int)x0f, y0 = (int)y0f;
        int x1 = x0 + 1, y1 = y0 + 1;
        float wx0 = ((unsigned)x0 < (unsigned)WIx) ? (1.f - fx) : 0.f;
        float wx1 = ((unsigned)x1 < (unsigned)WIx) ? fx : 0.f;
        float wy0 = ((unsigned)y0 < (unsigned)HIx) ? (1.f - fy) : 0.f;
        float wy1 = ((unsigned)y1 < (unsigned)HIx) ? fy : 0.f;
        int xc0 = min(max(x0, 0), WIx - 1), xc1 = min(max(x1, 0), WIx - 1);
        int yc0 = min(max(y0, 0), HIx - 1), yc1 = min(max(y1, 0), HIx - 1);
        float w00 = wx0 * wy0, w01 = wx1 * wy0, w10 = wx0 * wy1, w11 = wx1 * wy1;
        float4 v00 = xb[yc0 * WIx + xc0];
        float4 v01 = xb[yc0 * WIx + xc1];
        float4 v10 = xb[yc1 * WIx + xc0];
        float4 v11 = xb[yc1 * WIx + xc1];
        a0 += w00 * v00.x + w01 * v01.x + w10 * v10.x + w11 * v11.x;
        a1 += w00 * v00.y + w01 * v01.y + w10 * v10.y + w11 * v11.y;
        a2 += w00 * v00.z + w01 * v01.z + w10 * v10.z + w11 * v11.z;
    }

    // width-4 butterfly reduction
    a0 += __shfl_xor(a0, 1); a0 += __shfl_xor(a0, 2);
    a1 += __shfl_xor(a1, 1); a1 += __shfl_xor(a1, 2);
    a2 += __shfl_xor(a2, 1); a2 += __shfl_xor(a2, 2);

    if (lane4 == 0) {
        const float sc = 1.0f / (URx * UTx);
        int obase = b * (Cx * Hx * Wx) + oh * Wx + ow;
        out[obase]               = a0 * sc;
        out[obase + Hx * Wx]     = a1 * sc;
        out[obase + 2 * Hx * Wx] = a2 * sc;
    }
}

extern "C" void kernel_launch(void* const* d_in, const int* in_sizes, int n_in,
                              void* d_out, int out_size, void* d_ws, size_t ws_size,
                              hipStream_t stream) {
    const float*  x    = (const float*)d_in[0];
    const float*  lt   = (const float*)d_in[1];
    const float2* grid = (const float2*)d_in[2];
    float* out = (float*)d_out;

    float4* xt = (float4*)d_ws;
    const int total4 = Bx * HIx * WIx / 4;           // 802816
    transpose_hwc4<<<(total4 + 255) / 256, 256, 0, stream>>>((const float4*)x, xt);

    const int n_threads = 4 * Bx * Hx * Wx;          // 524288
    sample_hwc4<<<n_threads / 256, 256, 0, stream>>>(xt, lt, grid, out);
}

// Round 3
// 108.135 us; speedup vs baseline: 2.2838x; 2.0624x over previous
//
#include <hip/hip_runtime.h>

#define Bx 64
#define Cx 3
#define HIx 224
#define WIx 224
#define HWx (HIx*WIx)      // 50176
#define Hx 32
#define Wx 64
#define URx 10
#define UTx 10
#define HGx (URx*Hx)       // 320
#define WGx (Wx*UTx)       // 640

typedef unsigned int uint4a8 __attribute__((ext_vector_type(4), aligned(8)));

__device__ __forceinline__ unsigned short f2bf(float f) {
    unsigned u = __float_as_uint(f);
    return (unsigned short)((u + 0x7fffu + ((u >> 16) & 1u)) >> 16);
}
__device__ __forceinline__ float bf_lo(unsigned u) { return __uint_as_float(u << 16); }
__device__ __forceinline__ float bf_hi(unsigned u) { return __uint_as_float(u & 0xffff0000u); }

// ---------- CHW fp32 -> HWC4 bf16 (8 B / pixel), fully coalesced ----------
__global__ __launch_bounds__(256)
void to_hwc4_bf16(const float* __restrict__ x, uint2* __restrict__ xt) {
    int tid = blockIdx.x * blockDim.x + threadIdx.x;   // over B*HW = 3211264
    int b = tid / HWx;
    int hw = tid - b * HWx;
    const float* xb = x + (size_t)b * Cx * HWx + hw;
    float c0 = xb[0];
    float c1 = xb[HWx];
    float c2 = xb[2 * HWx];
    uint2 p;
    p.x = (unsigned)f2bf(c0) | ((unsigned)f2bf(c1) << 16);
    p.y = (unsigned)f2bf(c2);
    xt[tid] = p;
}

// ---------- sampler: 4 lanes/pixel, strided samples, 2x16B gathers --------
__global__ __launch_bounds__(256)
void sample_bf16(const uint2* __restrict__ xt,
                 const float* __restrict__ lt,
                 const float2* __restrict__ grid,
                 float* __restrict__ out) {
    // XCD swizzle: 32 blocks per image, all on one XCD (blockIdx % 8 heuristic)
    int bx = blockIdx.x;                 // [0, 2048)
    int xcd = bx & 7;
    int sub = (bx >> 3) & 7;
    int i   = bx >> 6;                   // [0, 32) block-within-image
    int b   = xcd * 8 + sub;             // [0, 64)

    int lane4 = threadIdx.x & 3;
    int pix = i * 64 + (threadIdx.x >> 2);  // [0, 2048) pixel within image
    int oh = pix >> 6;
    int ow = pix & 63;

    float lx = lt[2 * b];
    float ly = lt[2 * b + 1];
    float cxc = fmaf(lx, (WIx * 0.5f), (WIx - 1) * 0.5f);
    float cyc = fmaf(ly, (HIx * 0.5f), (HIx - 1) * 0.5f);

    const uint2* xb = xt + (size_t)b * HWx;
    int gbase = (oh * URx) * WGx + ow * UTx;

    float a0 = 0.f, a1 = 0.f, a2 = 0.f;
#pragma unroll 5
    for (int t = 0; t < 25; ++t) {
        int s = 4 * t + lane4;           // adjacent lanes -> adjacent angles
        int gi = s / 10;
        int gj = s - 10 * gi;
        float2 g = grid[gbase + gi * WGx + gj];
        float ix = fmaf(g.x, (WIx * 0.5f), cxc);   // guaranteed in [10.7, 212.3]
        float iy = fmaf(g.y, (HIx * 0.5f), cyc);
        int x0 = (int)ix;                // trunc == floor (positive)
        int y0 = (int)iy;
        float fx = ix - (float)x0;
        float fy = iy - (float)y0;

        const uint2* p = xb + y0 * WIx + x0;
        uint4a8 r0 = *(const uint4a8*)p;            // pixels (y0,x0),(y0,x0+1)
        uint4a8 r1 = *(const uint4a8*)(p + WIx);    // pixels (y1,x0),(y1,x0+1)

        // x-lerp per row, per channel: m = v0 + fx*(v1-v0)
        float m00 = fmaf(fx, bf_lo(r0.z) - bf_lo(r0.x), bf_lo(r0.x));
        float m01 = fmaf(fx, bf_hi(r0.z) - bf_hi(r0.x), bf_hi(r0.x));
        float m02 = fmaf(fx, bf_lo(r0.w) - bf_lo(r0.y), bf_lo(r0.y));
        float m10 = fmaf(fx, bf_lo(r1.z) - bf_lo(r1.x), bf_lo(r1.x));
        float m11 = fmaf(fx, bf_hi(r1.z) - bf_hi(r1.x), bf_hi(r1.x));
        float m12 = fmaf(fx, bf_lo(r1.w) - bf_lo(r1.y), bf_lo(r1.y));
        // y-lerp and accumulate
        a0 += fmaf(fy, m10 - m00, m00);
        a1 += fmaf(fy, m11 - m01, m01);
        a2 += fmaf(fy, m12 - m02, m02);
    }

    a0 += __shfl_xor(a0, 1); a0 += __shfl_xor(a0, 2);
    a1 += __shfl_xor(a1, 1); a1 += __shfl_xor(a1, 2);
    a2 += __shfl_xor(a2, 1); a2 += __shfl_xor(a2, 2);

    if (lane4 == 0) {
        const float sc = 1.0f / (URx * UTx);
        int obase = b * (Cx * Hx * Wx) + oh * Wx + ow;
        out[obase]               = a0 * sc;
        out[obase + Hx * Wx]     = a1 * sc;
        out[obase + 2 * Hx * Wx] = a2 * sc;
    }
}

extern "C" void kernel_launch(void* const* d_in, const int* in_sizes, int n_in,
                              void* d_out, int out_size, void* d_ws, size_t ws_size,
                              hipStream_t stream) {
    const float*  x    = (const float*)d_in[0];
    const float*  lt   = (const float*)d_in[1];
    const float2* grid = (const float2*)d_in[2];
    float* out = (float*)d_out;

    uint2* xt = (uint2*)d_ws;                        // 64*50176*8 B = 25.7 MB
    const int total = Bx * HWx;                      // 3211264
    to_hwc4_bf16<<<total / 256, 256, 0, stream>>>(x, xt);

    const int n_threads = 4 * Bx * Hx * Wx;          // 524288
    sample_bf16<<<n_threads / 256, 256, 0, stream>>>(xt, lt, grid, out);
}